// Round 9
// baseline (310.024 us; speedup 1.0000x reference)
//
#include <hip/hip_runtime.h>
#include <math.h>

#define NN  50000
#define NNP 50048
#define NE  800000
#define REP 16

// ---- workspace byte offsets ----
#define B_BG1   0u          // g1 B frags: 12 tiles x 2 ks x 512 bf16 = 24576 B
#define B_BG2A  24576u      // g2 grp1 frags: 4 x 10 x 512 bf16 = 40960 B
#define B_BG2B  65536u      // g2 grp2 frags: 4 x 8 x 512 bf16 = 32768 B
#define B_BG3   98304u      // g3 stacked frags: 16 x 4 x 512 bf16 = 65536 B
#define B_WE2   163840u     // 3x64 f32
#define B_BE2   164608u     // 64 f32
#define B_B4    164864u     // 256 f32 GRU bias [b3r+bhhr | b3z+bhhz | b3n | bhhn]
#define B_SUML  165888u     // 1 f32
#define B_XB    166912u     // x bf16: NNP*64
#define B_NF    6573056u    // [md2|ms2] bf16: NNP*128 (256 B/row)
#define B_A2    19385344u   // [m | o1-interleaved] bf16: NNP*320 (640 B/row)
#define B_S2F   51416064u   // NN f32
#define B_CNT   51616064u   // REP*NN int
#define B_OFFS  54816064u   // NN+1 int
#define B_RANK  55016072u   // NE int
#define B_ROFF  58216072u   // NN*REP int
#define B_EL2   61416072u   // NE int2 (e, src)
#define B_PART  67816072u   // 196 int
// end ~67.8 MB

#define SCAN_B  196

typedef __attribute__((ext_vector_type(8))) short s8v;
typedef __attribute__((ext_vector_type(4))) short s4v;
typedef __attribute__((ext_vector_type(4))) float f4v;

__device__ inline short f2b(float f){
    union { float f; unsigned u; } v; v.f = f;
    unsigned r = v.u + 0x7fffu + ((v.u >> 16) & 1u);
    return (short)(r >> 16);
}
__device__ inline float b2f(short b){
    union { unsigned u; float f; } v; v.u = ((unsigned)(unsigned short)b) << 16;
    return v.f;
}

// ---- k_prep: weight fold/pack + xcast + replicated count(+rank) + avglog ----
// ALL 3125 blocks: count+rank (3125*256 == NE). blocks 0..41: pack;
// 42..1604: xcast; 1605..1800: avglog.
__global__ __launch_bounds__(256) void k_prep(const float* __restrict__ x,
    const float* __restrict__ dh, const int* __restrict__ dstA,
    const float* __restrict__ W, const float* __restrict__ Wpre,
    const float* __restrict__ We, const float* __restrict__ be,
    const float* __restrict__ bpost, const float* __restrict__ Wpost,
    const float* __restrict__ Wih, const float* __restrict__ bih,
    const float* __restrict__ Whh, const float* __restrict__ bhh,
    int* __restrict__ cnt, int* __restrict__ rank,
    unsigned char* __restrict__ wsb)
{
    __shared__ float sred[4];
    int b = blockIdx.x, t = threadIdx.x;
    {   // degree count + rank into replica (b & 15)
        int e = b * 256 + t;
        int r = b & (REP - 1);
        rank[e] = atomicAdd(&cnt[r * NN + dstA[e]], 1);
    }

    if (b < 42) {                            // job: weight fold + MFMA-frag pack
        int idx = b * 256 + t;
        int lane = idx & 63;
        int quad = lane >> 4, l15 = lane & 15;
        if (idx < 1536) {                    // bg1: [W | U1 | U2] (64 x 192)
            short* dst = (short*)(wsb + B_BG1);
            int ts = idx >> 6;               // 0..23 = tile*2+s
            int tt = ts >> 1, s = ts & 1;
            int n = tt*16 + l15;
            for (int j = 0; j < 8; ++j) {
                int k = s*32 + quad*8 + j;
                float v;
                if (n < 64)       v = W[k*64 + n];
                else if (n < 128) { v = 0.f; for (int c = 0; c < 64; ++c) v += W[k*64+c]*Wpre[c*64 + (n-64)]; }
                else              { v = 0.f; for (int c = 0; c < 64; ++c) v += W[k*64+c]*Wpre[4096 + c*64 + (n-128)]; }
                dst[((size_t)ts*64 + lane)*8 + j] = f2b(v);
            }
        } else if (idx < 4096) {             // bg2a: [Wp_m; W1+W3 interleaved-K] (320 x 64)
            int id = idx - 1536;
            short* dst = (short*)(wsb + B_BG2A);
            int ts = id >> 6;                // tt*10+s
            int tt = ts / 10, s = ts % 10;
            int n = tt*16 + l15;
            for (int j = 0; j < 8; ++j) {
                int k = s*32 + quad*8 + j;   // 0..319 (a2 K order)
                float v;
                if (k < 64) v = Wpost[k*64 + n];
                else {                       // o1 interleaved: k=64+ch*4+st
                    int kk = k - 64, ch = kk >> 2, st = kk & 3;
                    int ok = 64 + st*64 + ch;
                    v = Wpost[ok*64 + n] + Wpost[(ok + 512)*64 + n];  // o3==o1 fold
                }
                dst[((size_t)ts*64 + lane)*8 + j] = f2b(v);
            }
        } else if (idx < 6144) {             // bg2b: W2 interleaved-K (256 x 64)
            int id = idx - 4096;
            short* dst = (short*)(wsb + B_BG2B);
            int ts = id >> 6;                // tt*8+s
            int tt = ts / 8, s = ts % 8;
            int n = tt*16 + l15;
            for (int j = 0; j < 8; ++j) {
                int k = s*32 + quad*8 + j;
                int ch = k >> 2, st = k & 3;
                int ok = 320 + st*64 + ch;
                dst[((size_t)ts*64 + lane)*8 + j] = f2b(Wpost[ok*64 + n]);
            }
        } else if (idx < 10240) {            // bg3: [[Wih_r,Wih_z,Wih_n,0],[Whh_r,Whh_z,0,Whh_n]] (128 x 256)
            int id = idx - 6144;
            short* dst = (short*)(wsb + B_BG3);
            int ts = id >> 6;                // 0..63 = tile*4+s
            int tt = ts >> 2, s = ts & 3;
            int n = tt*16 + l15;             // 0..255
            for (int j = 0; j < 8; ++j) {
                int k = s*32 + quad*8 + j;   // 0..127
                float v;
                if (k < 64) v = (n < 192) ? Wih[k*192 + n] : 0.f;
                else {
                    int kk = k - 64;
                    if (n < 128)      v = Whh[kk*192 + n];
                    else if (n < 192) v = 0.f;
                    else              v = Whh[kk*192 + 128 + (n - 192)];
                }
                dst[((size_t)ts*64 + lane)*8 + j] = f2b(v);
            }
        } else if (idx < 10432) {            // We2 = We @ Wpre3 (3 x 64)
            int t2 = idx - 10240; int kk = t2 >> 6, j = t2 & 63;
            float v = 0.f;
            for (int c = 0; c < 64; ++c) v += We[kk*64 + c] * Wpre[(128+c)*64 + j];
            ((float*)(wsb + B_WE2))[t2] = v;
        } else if (idx < 10496) {            // be2 = be @ Wpre3
            int j = idx - 10432;
            float v = 0.f;
            for (int c = 0; c < 64; ++c) v += be[c] * Wpre[(128+c)*64 + j];
            ((float*)(wsb + B_BE2))[j] = v;
        } else if (idx < 10752) {            // b4 GRU bias table (256)
            int j = idx - 10496;
            float v;
            if (j < 192) {
                v = bih[j];
                for (int k = 0; k < 64; ++k) v += bpost[k] * Wih[k*192 + j];
                if (j < 128) v += bhh[j];
            } else v = bhh[128 + (j - 192)];
            ((float*)(wsb + B_B4))[j] = v;
        }
    } else if (b < 1605) {                   // job: x -> bf16
        int i = (b - 42) * 256 + t;
        if (i < 400000) {
            const float4* xp = (const float4*)(x + (size_t)i * 8);
            float4 p0 = xp[0], p1 = xp[1];
            s8v o;
            o[0]=f2b(p0.x); o[1]=f2b(p0.y); o[2]=f2b(p0.z); o[3]=f2b(p0.w);
            o[4]=f2b(p1.x); o[5]=f2b(p1.y); o[6]=f2b(p1.z); o[7]=f2b(p1.w);
            *(s8v*)((short*)(wsb + B_XB) + (size_t)i * 8) = o;
        }
    } else if (b < 1801) {                   // job: sum log(dh+1)
        int i = (b - 1605) * 256 + t;
        float v = (i < NN) ? logf(dh[i] + 1.f) : 0.f;
        #pragma unroll
        for (int m = 32; m >= 1; m >>= 1) v += __shfl_xor(v, m, 64);
        if ((t & 63) == 0) sred[t >> 6] = v;
        __syncthreads();
        if (t == 0) atomicAdd((float*)(wsb + B_SUML), sred[0]+sred[1]+sred[2]+sred[3]);
    }
}

// ---- scanA: per-node replica prefix -> roff; block scan of totals ----
__global__ __launch_bounds__(256) void k_scanA(const int* __restrict__ cnt,
    int* __restrict__ offs, int* __restrict__ roff, int* __restrict__ part)
{
    __shared__ int sh[256];
    int t = threadIdx.x, i = blockIdx.x * 256 + t;
    int v = 0;
    int pre[REP];
    if (i < NN) {
        #pragma unroll
        for (int r = 0; r < REP; ++r) { pre[r] = v; v += cnt[r * NN + i]; }
    }
    sh[t] = v; __syncthreads();
    #pragma unroll
    for (int o = 1; o < 256; o <<= 1) {
        int u = (t >= o) ? sh[t - o] : 0;
        __syncthreads();
        sh[t] += u;
        __syncthreads();
    }
    if (i < NN) {
        offs[i] = sh[t] - v;
        int4* rp = (int4*)(roff + (size_t)i * REP);
        #pragma unroll
        for (int q = 0; q < REP/4; ++q)
            rp[q] = make_int4(pre[q*4], pre[q*4+1], pre[q*4+2], pre[q*4+3]);
    }
    if (t == 255) part[blockIdx.x] = sh[255];
}

// ---- scanC: absolutize offs and roff ----
__global__ __launch_bounds__(256) void k_scanC(const int* __restrict__ part,
    int* __restrict__ offs, int* __restrict__ roff)
{
    __shared__ int sh[256];
    int b = blockIdx.x, t = threadIdx.x;
    int v = (t < SCAN_B) ? part[t] : 0;
    sh[t] = v; __syncthreads();
    #pragma unroll
    for (int o = 1; o < 256; o <<= 1) {
        int u = (t >= o) ? sh[t - o] : 0;
        __syncthreads();
        sh[t] += u;
        __syncthreads();
    }
    int base = (b == 0) ? 0 : sh[b - 1];
    int i = b * 256 + t;
    if (i < NN) {
        int fo = offs[i] + base;
        offs[i] = fo;
        int4* rp = (int4*)(roff + (size_t)i * REP);
        #pragma unroll
        for (int q = 0; q < REP/4; ++q) {
            int4 r4 = rp[q];
            r4.x += fo; r4.y += fo; r4.z += fo; r4.w += fo;
            rp[q] = r4;
        }
    }
    if (b == 0 && t == 0) offs[NN] = NE;
}

// ---- scatter: p = roff[dst][replica] + rank — no atomics ----
__global__ __launch_bounds__(256) void k_scatter(const int* __restrict__ srcA,
    const int* __restrict__ dstA, const int* __restrict__ rank,
    const int* __restrict__ roff, int2* __restrict__ el2)
{
    int e = blockIdx.x * 256 + threadIdx.x;
    int r = blockIdx.x & (REP - 1);
    int dst = dstA[e];
    int p = roff[dst * REP + r] + rank[e];
    el2[p] = make_int2(e, srcA[e]);
}

// ---- G1 (MFMA): x @ [W|U1|U2] -> a2(m), nf(md2|ms2) ----
__global__ __launch_bounds__(256) void k_g1(unsigned char* __restrict__ wsb)
{
    const short* xb = (const short*)(wsb + B_XB);
    const short* bf = (const short*)(wsb + B_BG1);
    short* a2 = (short*)(wsb + B_A2);
    short* nf = (short*)(wsb + B_NF);
    int w = threadIdx.x >> 6, lane = threadIdx.x & 63;
    int quad = lane >> 4, l15 = lane & 15;
    int R0 = blockIdx.x * 64 + w * 16;
    const short* arow = xb + (size_t)(R0 + l15) * 64 + quad * 8;
    s8v a0 = *(const s8v*)(arow);
    s8v a1 = *(const s8v*)(arow + 32);
    f4v acc[12];
    #pragma unroll
    for (int t = 0; t < 12; ++t) acc[t] = (f4v){0.f,0.f,0.f,0.f};
    #pragma unroll
    for (int t = 0; t < 12; ++t) {
        s8v b0 = *(const s8v*)(bf + ((size_t)(t*2+0)*64 + lane)*8);
        s8v b1 = *(const s8v*)(bf + ((size_t)(t*2+1)*64 + lane)*8);
        acc[t] = __builtin_amdgcn_mfma_f32_16x16x32_bf16(a0, b0, acc[t], 0, 0, 0);
        acc[t] = __builtin_amdgcn_mfma_f32_16x16x32_bf16(a1, b1, acc[t], 0, 0, 0);
    }
    #pragma unroll
    for (int t = 0; t < 12; ++t) {
        #pragma unroll
        for (int r = 0; r < 4; ++r) {
            int row = R0 + quad*4 + r;
            if (row >= NN) continue;
            short v = f2b(acc[t][r]);
            if (t < 4) a2[(size_t)row*320 + t*16 + l15] = v;
            else       nf[(size_t)row*128 + (t-4)*16 + l15] = v;
        }
    }
}

// ---- aggregation: grid-stride wave-per-node; o1 interleaved bf16x4 store ----
__global__ __launch_bounds__(256) void k_agg(const float* __restrict__ eattr,
    const float* __restrict__ bpre, unsigned char* __restrict__ wsb)
{
    __shared__ float4 sEA[4][64];
    __shared__ int    sOFF[4][64];
    int lane = threadIdx.x & 63;
    int w    = threadIdx.x >> 6;
    int wid  = blockIdx.x * 4 + w;
    const int* offs = (const int*)(wsb + B_OFFS);
    const int2* el2 = (const int2*)(wsb + B_EL2);
    const unsigned char* nfb = wsb + B_NF;
    const short* nf = (const short*)(wsb + B_NF);
    const float* we2p = (const float*)(wsb + B_WE2);
    float we0 = we2p[lane], we1 = we2p[64 + lane], we2v = we2p[128 + lane];
    float be2l = ((const float*)(wsb + B_BE2))[lane];
    float bprel = bpre[lane];
    float rcpavg = (float)NN / ((const float*)(wsb + B_SUML))[0];
    const float4* e4 = (const float4*)eattr;
    unsigned laneoff = 128u + 2u * (unsigned)lane;
    short* a2b = (short*)(wsb + B_A2);
    float* s2f = (float*)(wsb + B_S2F);

    for (int n = wid; n < NN; n += 8192) {
        float md2l = b2f(nf[(size_t)n * 128 + lane]);
        float tbase = md2l + be2l;
        int o0 = offs[n], o1e = offs[n + 1];
        float s = 0.f, ss = 0.f, mn = INFINITY, mx = -INFINITY;
        for (int base = o0; base < o1e; base += 64) {
            int cnt = o1e - base; if (cnt > 64) cnt = 64;
            if (lane < cnt) {
                int2 es = el2[base + lane];
                sOFF[w][lane] = es.y << 8;
                sEA[w][lane]  = e4[es.x];
            }
            for (int d0 = 0; d0 < cnt; d0 += 8) {
                float msv[8];
                #pragma unroll
                for (int u = 0; u < 8; ++u) {
                    int d = d0 + u; if (d > cnt - 1) d = cnt - 1;
                    unsigned off = (unsigned)sOFF[w][d] + laneoff;
                    msv[u] = b2f(*(const short*)(nfb + off));
                }
                #pragma unroll
                for (int u = 0; u < 8; ++u) {
                    int d = d0 + u;
                    if (d < cnt) {
                        float4 ea = sEA[w][d];
                        float t = tbase + msv[u];
                        t = fmaf(ea.x, we0, t);
                        t = fmaf(ea.y, we1, t);
                        t = fmaf(ea.z, we2v, t);
                        float h = fmaf(ea.w, t, bprel);
                        s += h; ss = fmaf(h, h, ss);
                        mn = fminf(mn, h); mx = fmaxf(mx, h);
                    }
                }
            }
        }
        int deg = o1e - o0;
        float safe = (float)(deg > 0 ? deg : 1);
        float mean = s / safe;
        float var  = ss / safe - mean * mean;
        float stdv = sqrtf(fmaxf(var, 0.f) + 1e-5f);
        if (deg == 0) { mn = 0.f; mx = 0.f; }
        s4v o; o[0] = f2b(mean); o[1] = f2b(mn); o[2] = f2b(mx); o[3] = f2b(stdv);
        *(s4v*)(a2b + (size_t)n * 320 + 64 + (lane << 2)) = o;
        if (lane == 0) s2f[n] = logf(safe + 1.f) * rcpavg;
    }
}

// ---- G2+G3 fused: G3 = [out_pre | x] @ B4 (K=128, N=256) -> GRU, no gh ----
__global__ __launch_bounds__(256) void k_g23(const float* __restrict__ x,
    unsigned char* __restrict__ wsb, float* __restrict__ out)
{
    __shared__ short sm[64 * 72];            // out_pre tile, row stride 72
    __shared__ float sS2[64];
    const short* a2  = (const short*)(wsb + B_A2);
    const short* xb  = (const short*)(wsb + B_XB);
    const short* bgA = (const short*)(wsb + B_BG2A);
    const short* bgB = (const short*)(wsb + B_BG2B);
    const short* bg3 = (const short*)(wsb + B_BG3);
    const float* b4  = (const float*)(wsb + B_B4);
    const float* s2f = (const float*)(wsb + B_S2F);
    int w = threadIdx.x >> 6, lane = threadIdx.x & 63;
    int quad = lane >> 4, l15 = lane & 15;
    int R0 = blockIdx.x * 64 + w * 16;

    // prefetch x bf16 row for G3 (address known early)
    const short* xrow = xb + (size_t)(R0 + l15) * 64 + quad * 8;
    s8v q0 = *(const s8v*)(xrow);
    s8v q1 = *(const s8v*)(xrow + 32);

    {   // s2 tile
        int i = threadIdx.x;
        if (i < 64) {
            int row = blockIdx.x * 64 + i;
            sS2[i] = (row < NN) ? s2f[row] : 0.f;
        }
    }

    // ---- G2 ----
    const short* aBase = a2 + (size_t)(R0 + l15) * 320 + quad * 8;
    f4v acc1[4], acc2[4];
    #pragma unroll
    for (int t = 0; t < 4; ++t) { acc1[t] = (f4v){0.f,0.f,0.f,0.f}; acc2[t] = (f4v){0.f,0.f,0.f,0.f}; }
    #pragma unroll 2
    for (int s = 0; s < 10; ++s) {           // grp1: K=320 over [m|o1]
        s8v a = *(const s8v*)(aBase + s * 32);
        #pragma unroll
        for (int t = 0; t < 4; ++t) {
            s8v b = *(const s8v*)(bgA + ((size_t)(t*10 + s)*64 + lane)*8);
            acc1[t] = __builtin_amdgcn_mfma_f32_16x16x32_bf16(a, b, acc1[t], 0, 0, 0);
        }
    }
    #pragma unroll 2
    for (int s = 0; s < 8; ++s) {            // grp2: K=256 over o1
        s8v a = *(const s8v*)(aBase + 64 + s * 32);
        #pragma unroll
        for (int t = 0; t < 4; ++t) {
            s8v b = *(const s8v*)(bgB + ((size_t)(t*8 + s)*64 + lane)*8);
            acc2[t] = __builtin_amdgcn_mfma_f32_16x16x32_bf16(a, b, acc2[t], 0, 0, 0);
        }
    }
    __syncthreads();
    #pragma unroll
    for (int t = 0; t < 4; ++t)
        #pragma unroll
        for (int r = 0; r < 4; ++r) {
            int lr = w*16 + quad*4 + r;
            float v = acc1[t][r] + sS2[lr] * acc2[t][r];
            sm[lr * 72 + t*16 + l15] = f2b(v);
        }
    __syncthreads();

    // ---- G3: A = [out_pre | x], B = stacked table ----
    const short* arow = sm + (w*16 + l15) * 72 + quad * 8;
    s8v p0 = *(const s8v*)(arow);
    s8v p1 = *(const s8v*)(arow + 32);
    f4v acc[16];
    #pragma unroll
    for (int t = 0; t < 16; ++t) acc[t] = (f4v){0.f,0.f,0.f,0.f};
    #pragma unroll 4
    for (int t = 0; t < 16; ++t) {
        s8v b0 = *(const s8v*)(bg3 + ((size_t)(t*4+0)*64 + lane)*8);
        s8v b1 = *(const s8v*)(bg3 + ((size_t)(t*4+1)*64 + lane)*8);
        s8v b2 = *(const s8v*)(bg3 + ((size_t)(t*4+2)*64 + lane)*8);
        s8v b3v= *(const s8v*)(bg3 + ((size_t)(t*4+3)*64 + lane)*8);
        acc[t] = __builtin_amdgcn_mfma_f32_16x16x32_bf16(p0, b0, acc[t], 0, 0, 0);
        acc[t] = __builtin_amdgcn_mfma_f32_16x16x32_bf16(p1, b1, acc[t], 0, 0, 0);
        acc[t] = __builtin_amdgcn_mfma_f32_16x16x32_bf16(q0, b2, acc[t], 0, 0, 0);
        acc[t] = __builtin_amdgcn_mfma_f32_16x16x32_bf16(q1, b3v, acc[t], 0, 0, 0);
    }
    // ---- GRU epilogue: everything in registers ----
    #pragma unroll
    for (int t = 0; t < 4; ++t) {
        #pragma unroll
        for (int r = 0; r < 4; ++r) {
            int row = R0 + quad*4 + r;
            if (row >= NN) continue;
            int c = t*16 + l15;
            float srz = acc[t][r]    + b4[c];         // ir+hr
            float szz = acc[t+4][r]  + b4[64 + c];    // iz+hz
            float inn = acc[t+8][r]  + b4[128 + c];   // i_n
            float hnn = acc[t+12][r] + b4[192 + c];   // h_n
            float rr = 1.f / (1.f + expf(-srz));
            float zz = 1.f / (1.f + expf(-szz));
            float nn = tanhf(fmaf(rr, hnn, inn));
            out[(size_t)row*64 + c] = (1.f - zz)*nn + zz*x[(size_t)row*64 + c];
        }
    }
}

extern "C" void kernel_launch(void* const* d_in, const int* in_sizes, int n_in,
                              void* d_out, int out_size, void* d_ws, size_t ws_size,
                              hipStream_t stream)
{
    const float* x     = (const float*)d_in[0];
    const float* eattr = (const float*)d_in[1];
    const float* dh    = (const float*)d_in[2];
    const float* W     = (const float*)d_in[3];
    const float* We    = (const float*)d_in[4];
    const float* be    = (const float*)d_in[5];
    const float* Wpre  = (const float*)d_in[6];
    const float* bpre  = (const float*)d_in[7];
    const float* Wpost = (const float*)d_in[8];
    const float* bpost = (const float*)d_in[9];
    const float* Wih   = (const float*)d_in[10];
    const float* bih   = (const float*)d_in[11];
    const float* Whh   = (const float*)d_in[12];
    const float* bhh   = (const float*)d_in[13];
    const int*   eidx  = (const int*)d_in[14];
    unsigned char* wsb = (unsigned char*)d_ws;
    float* out = (float*)d_out;
    const int* srcA = eidx;
    const int* dstA = eidx + NE;
    int* cnt  = (int*)(wsb + B_CNT);
    int* offs = (int*)(wsb + B_OFFS);
    int* rank = (int*)(wsb + B_RANK);
    int* roff = (int*)(wsb + B_ROFF);
    int2* el2 = (int2*)(wsb + B_EL2);
    int* part = (int*)(wsb + B_PART);

    hipMemsetAsync(wsb + B_SUML, 0, 4, stream);
    hipMemsetAsync(cnt, 0, REP * NN * sizeof(int), stream);

    k_prep    <<<3125, 256, 0, stream>>>(x, dh, dstA, W, Wpre, We, be, bpost,
                                         Wpost, Wih, bih, Whh, bhh, cnt, rank, wsb);
    k_scanA   <<<SCAN_B, 256, 0, stream>>>(cnt, offs, roff, part);
    k_scanC   <<<SCAN_B, 256, 0, stream>>>(part, offs, roff);
    k_scatter <<<NE/256, 256, 0, stream>>>(srcA, dstA, rank, roff, el2);
    k_g1      <<<NNP/64, 256, 0, stream>>>(wsb);
    k_agg     <<<2048, 256, 0, stream>>>(eattr, bpre, wsb);
    k_g23     <<<NNP/64, 256, 0, stream>>>(x, wsb, out);
}

// Round 10
// 254.011 us; speedup vs baseline: 1.2205x; 1.2205x over previous
//
#include <hip/hip_runtime.h>
#include <math.h>

#define NN  50000
#define NNP 50048
#define NE  800000
#define REP 16

// ---- workspace byte offsets ----
#define B_BG1   0u          // g1 B frags: 12 tiles x 2 ks x 512 bf16 = 24576 B
#define B_BG2A  24576u      // g2 grp1 frags: 4 x 10 x 512 bf16 = 40960 B
#define B_BG2B  65536u      // g2 grp2 frags: 4 x 8 x 512 bf16 = 32768 B
#define B_BG3   98304u      // g3 stacked frags: 16 x 4 x 512 bf16 = 65536 B
#define B_WE2   163840u     // 3x64 f32
#define B_BE2   164608u     // 64 f32
#define B_B4    164864u     // 256 f32 GRU bias [b3r+bhhr | b3z+bhhz | b3n | bhhn]
#define B_SUML  165888u     // 1 f32
#define B_XB    166912u     // x bf16: NNP*64
#define B_NF    6573056u    // [md2|ms2] bf16: NNP*128 (256 B/row)
#define B_A2    19385344u   // [m | o1-interleaved] bf16: NNP*320 (640 B/row)
#define B_S2F   51416064u   // NN f32
#define B_CNT   51616064u   // REP*NN int
#define B_OFFS  54816064u   // NN+1 int
#define B_RANK  55016072u   // NE int
#define B_ROFF  58216072u   // NN*REP int
#define B_EL2   61416072u   // NE int2 (e, src)
#define B_PART  67816072u   // 196 int
// end ~67.8 MB

#define SCAN_B  196

typedef __attribute__((ext_vector_type(8))) short s8v;
typedef __attribute__((ext_vector_type(4))) short s4v;
typedef __attribute__((ext_vector_type(4))) float f4v;

__device__ inline short f2b(float f){
    union { float f; unsigned u; } v; v.f = f;
    unsigned r = v.u + 0x7fffu + ((v.u >> 16) & 1u);
    return (short)(r >> 16);
}
__device__ inline float b2f(short b){
    union { unsigned u; float f; } v; v.u = ((unsigned)(unsigned short)b) << 16;
    return v.f;
}

// ---- k_prep: weight fold/pack + xcast + replicated count(+rank) + avglog ----
__global__ __launch_bounds__(256) void k_prep(const float* __restrict__ x,
    const float* __restrict__ dh, const int* __restrict__ dstA,
    const float* __restrict__ W, const float* __restrict__ Wpre,
    const float* __restrict__ We, const float* __restrict__ be,
    const float* __restrict__ bpost, const float* __restrict__ Wpost,
    const float* __restrict__ Wih, const float* __restrict__ bih,
    const float* __restrict__ Whh, const float* __restrict__ bhh,
    int* __restrict__ cnt, int* __restrict__ rank,
    unsigned char* __restrict__ wsb)
{
    __shared__ float sred[4];
    int b = blockIdx.x, t = threadIdx.x;
    {   // degree count + rank into replica (b & 15)
        int e = b * 256 + t;
        int r = b & (REP - 1);
        rank[e] = atomicAdd(&cnt[r * NN + dstA[e]], 1);
    }

    if (b < 42) {                            // job: weight fold + MFMA-frag pack
        int idx = b * 256 + t;
        int lane = idx & 63;
        int quad = lane >> 4, l15 = lane & 15;
        if (idx < 1536) {                    // bg1: [W | U1 | U2] (64 x 192)
            short* dst = (short*)(wsb + B_BG1);
            int ts = idx >> 6;               // 0..23 = tile*2+s
            int tt = ts >> 1, s = ts & 1;
            int n = tt*16 + l15;
            for (int j = 0; j < 8; ++j) {
                int k = s*32 + quad*8 + j;
                float v;
                if (n < 64)       v = W[k*64 + n];
                else if (n < 128) { v = 0.f; for (int c = 0; c < 64; ++c) v += W[k*64+c]*Wpre[c*64 + (n-64)]; }
                else              { v = 0.f; for (int c = 0; c < 64; ++c) v += W[k*64+c]*Wpre[4096 + c*64 + (n-128)]; }
                dst[((size_t)ts*64 + lane)*8 + j] = f2b(v);
            }
        } else if (idx < 4096) {             // bg2a: [Wp_m; W1+W3 interleaved-K] (320 x 64)
            int id = idx - 1536;
            short* dst = (short*)(wsb + B_BG2A);
            int ts = id >> 6;                // tt*10+s
            int tt = ts / 10, s = ts % 10;
            int n = tt*16 + l15;
            for (int j = 0; j < 8; ++j) {
                int k = s*32 + quad*8 + j;   // 0..319 (a2 K order)
                float v;
                if (k < 64) v = Wpost[k*64 + n];
                else {                       // o1 interleaved: k=64+ch*4+st
                    int kk = k - 64, ch = kk >> 2, st = kk & 3;
                    int ok = 64 + st*64 + ch;
                    v = Wpost[ok*64 + n] + Wpost[(ok + 512)*64 + n];  // o3==o1 fold
                }
                dst[((size_t)ts*64 + lane)*8 + j] = f2b(v);
            }
        } else if (idx < 6144) {             // bg2b: W2 interleaved-K (256 x 64)
            int id = idx - 4096;
            short* dst = (short*)(wsb + B_BG2B);
            int ts = id >> 6;                // tt*8+s
            int tt = ts / 8, s = ts % 8;
            int n = tt*16 + l15;
            for (int j = 0; j < 8; ++j) {
                int k = s*32 + quad*8 + j;
                int ch = k >> 2, st = k & 3;
                int ok = 320 + st*64 + ch;
                dst[((size_t)ts*64 + lane)*8 + j] = f2b(Wpost[ok*64 + n]);
            }
        } else if (idx < 10240) {            // bg3: [[Wih_r,Wih_z,Wih_n,0],[Whh_r,Whh_z,0,Whh_n]] (128 x 256)
            int id = idx - 6144;
            short* dst = (short*)(wsb + B_BG3);
            int ts = id >> 6;                // 0..63 = tile*4+s
            int tt = ts >> 2, s = ts & 3;
            int n = tt*16 + l15;             // 0..255
            for (int j = 0; j < 8; ++j) {
                int k = s*32 + quad*8 + j;   // 0..127
                float v;
                if (k < 64) v = (n < 192) ? Wih[k*192 + n] : 0.f;
                else {
                    int kk = k - 64;
                    if (n < 128)      v = Whh[kk*192 + n];
                    else if (n < 192) v = 0.f;
                    else              v = Whh[kk*192 + 128 + (n - 192)];
                }
                dst[((size_t)ts*64 + lane)*8 + j] = f2b(v);
            }
        } else if (idx < 10432) {            // We2 = We @ Wpre3 (3 x 64)
            int t2 = idx - 10240; int kk = t2 >> 6, j = t2 & 63;
            float v = 0.f;
            for (int c = 0; c < 64; ++c) v += We[kk*64 + c] * Wpre[(128+c)*64 + j];
            ((float*)(wsb + B_WE2))[t2] = v;
        } else if (idx < 10496) {            // be2 = be @ Wpre3
            int j = idx - 10432;
            float v = 0.f;
            for (int c = 0; c < 64; ++c) v += be[c] * Wpre[(128+c)*64 + j];
            ((float*)(wsb + B_BE2))[j] = v;
        } else if (idx < 10752) {            // b4 GRU bias table (256)
            int j = idx - 10496;
            float v;
            if (j < 192) {
                v = bih[j];
                for (int k = 0; k < 64; ++k) v += bpost[k] * Wih[k*192 + j];
                if (j < 128) v += bhh[j];
            } else v = bhh[128 + (j - 192)];
            ((float*)(wsb + B_B4))[j] = v;
        }
    } else if (b < 1605) {                   // job: x -> bf16
        int i = (b - 42) * 256 + t;
        if (i < 400000) {
            const float4* xp = (const float4*)(x + (size_t)i * 8);
            float4 p0 = xp[0], p1 = xp[1];
            s8v o;
            o[0]=f2b(p0.x); o[1]=f2b(p0.y); o[2]=f2b(p0.z); o[3]=f2b(p0.w);
            o[4]=f2b(p1.x); o[5]=f2b(p1.y); o[6]=f2b(p1.z); o[7]=f2b(p1.w);
            *(s8v*)((short*)(wsb + B_XB) + (size_t)i * 8) = o;
        }
    } else if (b < 1801) {                   // job: sum log(dh+1)
        int i = (b - 1605) * 256 + t;
        float v = (i < NN) ? logf(dh[i] + 1.f) : 0.f;
        #pragma unroll
        for (int m = 32; m >= 1; m >>= 1) v += __shfl_xor(v, m, 64);
        if ((t & 63) == 0) sred[t >> 6] = v;
        __syncthreads();
        if (t == 0) atomicAdd((float*)(wsb + B_SUML), sred[0]+sred[1]+sred[2]+sred[3]);
    }
}

// ---- scanA ----
__global__ __launch_bounds__(256) void k_scanA(const int* __restrict__ cnt,
    int* __restrict__ offs, int* __restrict__ roff, int* __restrict__ part)
{
    __shared__ int sh[256];
    int t = threadIdx.x, i = blockIdx.x * 256 + t;
    int v = 0;
    int pre[REP];
    if (i < NN) {
        #pragma unroll
        for (int r = 0; r < REP; ++r) { pre[r] = v; v += cnt[r * NN + i]; }
    }
    sh[t] = v; __syncthreads();
    #pragma unroll
    for (int o = 1; o < 256; o <<= 1) {
        int u = (t >= o) ? sh[t - o] : 0;
        __syncthreads();
        sh[t] += u;
        __syncthreads();
    }
    if (i < NN) {
        offs[i] = sh[t] - v;
        int4* rp = (int4*)(roff + (size_t)i * REP);
        #pragma unroll
        for (int q = 0; q < REP/4; ++q)
            rp[q] = make_int4(pre[q*4], pre[q*4+1], pre[q*4+2], pre[q*4+3]);
    }
    if (t == 255) part[blockIdx.x] = sh[255];
}

// ---- scanC ----
__global__ __launch_bounds__(256) void k_scanC(const int* __restrict__ part,
    int* __restrict__ offs, int* __restrict__ roff)
{
    __shared__ int sh[256];
    int b = blockIdx.x, t = threadIdx.x;
    int v = (t < SCAN_B) ? part[t] : 0;
    sh[t] = v; __syncthreads();
    #pragma unroll
    for (int o = 1; o < 256; o <<= 1) {
        int u = (t >= o) ? sh[t - o] : 0;
        __syncthreads();
        sh[t] += u;
        __syncthreads();
    }
    int base = (b == 0) ? 0 : sh[b - 1];
    int i = b * 256 + t;
    if (i < NN) {
        int fo = offs[i] + base;
        offs[i] = fo;
        int4* rp = (int4*)(roff + (size_t)i * REP);
        #pragma unroll
        for (int q = 0; q < REP/4; ++q) {
            int4 r4 = rp[q];
            r4.x += fo; r4.y += fo; r4.z += fo; r4.w += fo;
            rp[q] = r4;
        }
    }
    if (b == 0 && t == 0) offs[NN] = NE;
}

// ---- scatter: no atomics ----
__global__ __launch_bounds__(256) void k_scatter(const int* __restrict__ srcA,
    const int* __restrict__ dstA, const int* __restrict__ rank,
    const int* __restrict__ roff, int2* __restrict__ el2)
{
    int e = blockIdx.x * 256 + threadIdx.x;
    int r = blockIdx.x & (REP - 1);
    int dst = dstA[e];
    int p = roff[dst * REP + r] + rank[e];
    el2[p] = make_int2(e, srcA[e]);
}

// ---- G1 (MFMA): x @ [W|U1|U2] -> a2(m), nf(md2|ms2) ----
__global__ __launch_bounds__(256) void k_g1(unsigned char* __restrict__ wsb)
{
    const short* xb = (const short*)(wsb + B_XB);
    const short* bf = (const short*)(wsb + B_BG1);
    short* a2 = (short*)(wsb + B_A2);
    short* nf = (short*)(wsb + B_NF);
    int w = threadIdx.x >> 6, lane = threadIdx.x & 63;
    int quad = lane >> 4, l15 = lane & 15;
    int R0 = blockIdx.x * 64 + w * 16;
    const short* arow = xb + (size_t)(R0 + l15) * 64 + quad * 8;
    s8v a0 = *(const s8v*)(arow);
    s8v a1 = *(const s8v*)(arow + 32);
    f4v acc[12];
    #pragma unroll
    for (int t = 0; t < 12; ++t) acc[t] = (f4v){0.f,0.f,0.f,0.f};
    #pragma unroll
    for (int t = 0; t < 12; ++t) {
        s8v b0 = *(const s8v*)(bf + ((size_t)(t*2+0)*64 + lane)*8);
        s8v b1 = *(const s8v*)(bf + ((size_t)(t*2+1)*64 + lane)*8);
        acc[t] = __builtin_amdgcn_mfma_f32_16x16x32_bf16(a0, b0, acc[t], 0, 0, 0);
        acc[t] = __builtin_amdgcn_mfma_f32_16x16x32_bf16(a1, b1, acc[t], 0, 0, 0);
    }
    #pragma unroll
    for (int t = 0; t < 12; ++t) {
        #pragma unroll
        for (int r = 0; r < 4; ++r) {
            int row = R0 + quad*4 + r;
            if (row >= NN) continue;
            short v = f2b(acc[t][r]);
            if (t < 4) a2[(size_t)row*320 + t*16 + l15] = v;
            else       nf[(size_t)row*128 + (t-4)*16 + l15] = v;
        }
    }
}

// ---- aggregation: grid-stride wave-per-node ----
__global__ __launch_bounds__(256) void k_agg(const float* __restrict__ eattr,
    const float* __restrict__ bpre, unsigned char* __restrict__ wsb)
{
    __shared__ float4 sEA[4][64];
    __shared__ int    sOFF[4][64];
    int lane = threadIdx.x & 63;
    int w    = threadIdx.x >> 6;
    int wid  = blockIdx.x * 4 + w;
    const int* offs = (const int*)(wsb + B_OFFS);
    const int2* el2 = (const int2*)(wsb + B_EL2);
    const unsigned char* nfb = wsb + B_NF;
    const short* nf = (const short*)(wsb + B_NF);
    const float* we2p = (const float*)(wsb + B_WE2);
    float we0 = we2p[lane], we1 = we2p[64 + lane], we2v = we2p[128 + lane];
    float be2l = ((const float*)(wsb + B_BE2))[lane];
    float bprel = bpre[lane];
    float rcpavg = (float)NN / ((const float*)(wsb + B_SUML))[0];
    const float4* e4 = (const float4*)eattr;
    unsigned laneoff = 128u + 2u * (unsigned)lane;
    short* a2b = (short*)(wsb + B_A2);
    float* s2f = (float*)(wsb + B_S2F);

    for (int n = wid; n < NN; n += 8192) {
        float md2l = b2f(nf[(size_t)n * 128 + lane]);
        float tbase = md2l + be2l;
        int o0 = offs[n], o1e = offs[n + 1];
        float s = 0.f, ss = 0.f, mn = INFINITY, mx = -INFINITY;
        for (int base = o0; base < o1e; base += 64) {
            int cnt = o1e - base; if (cnt > 64) cnt = 64;
            if (lane < cnt) {
                int2 es = el2[base + lane];
                sOFF[w][lane] = es.y << 8;
                sEA[w][lane]  = e4[es.x];
            }
            for (int d0 = 0; d0 < cnt; d0 += 8) {
                float msv[8];
                #pragma unroll
                for (int u = 0; u < 8; ++u) {
                    int d = d0 + u; if (d > cnt - 1) d = cnt - 1;
                    unsigned off = (unsigned)sOFF[w][d] + laneoff;
                    msv[u] = b2f(*(const short*)(nfb + off));
                }
                #pragma unroll
                for (int u = 0; u < 8; ++u) {
                    int d = d0 + u;
                    if (d < cnt) {
                        float4 ea = sEA[w][d];
                        float t = tbase + msv[u];
                        t = fmaf(ea.x, we0, t);
                        t = fmaf(ea.y, we1, t);
                        t = fmaf(ea.z, we2v, t);
                        float h = fmaf(ea.w, t, bprel);
                        s += h; ss = fmaf(h, h, ss);
                        mn = fminf(mn, h); mx = fmaxf(mx, h);
                    }
                }
            }
        }
        int deg = o1e - o0;
        float safe = (float)(deg > 0 ? deg : 1);
        float mean = s / safe;
        float var  = ss / safe - mean * mean;
        float stdv = sqrtf(fmaxf(var, 0.f) + 1e-5f);
        if (deg == 0) { mn = 0.f; mx = 0.f; }
        s4v o; o[0] = f2b(mean); o[1] = f2b(mn); o[2] = f2b(mx); o[3] = f2b(stdv);
        *(s4v*)(a2b + (size_t)n * 320 + 64 + (lane << 2)) = o;
        if (lane == 0) s2f[n] = logf(safe + 1.f) * rcpavg;
    }
}

// ---- G2+G3 fused: G3 = [out_pre | x] @ B4 stacked; one sub-tile t at a time ----
// Spill-free schedule: per t, 4 fresh gate accumulators -> 16 MFMAs -> GRU -> store.
__global__ __launch_bounds__(256) void k_g23(const float* __restrict__ x,
    unsigned char* __restrict__ wsb, float* __restrict__ out)
{
    __shared__ short sm[64 * 72];            // out_pre tile, row stride 72
    __shared__ float sS2[64];
    const short* a2  = (const short*)(wsb + B_A2);
    const short* xb  = (const short*)(wsb + B_XB);
    const short* bgA = (const short*)(wsb + B_BG2A);
    const short* bgB = (const short*)(wsb + B_BG2B);
    const short* bg3 = (const short*)(wsb + B_BG3);
    const float* b4  = (const float*)(wsb + B_B4);
    const float* s2f = (const float*)(wsb + B_S2F);
    int w = threadIdx.x >> 6, lane = threadIdx.x & 63;
    int quad = lane >> 4, l15 = lane & 15;
    int R0 = blockIdx.x * 64 + w * 16;

    {   // s2 tile
        int i = threadIdx.x;
        if (i < 64) {
            int row = blockIdx.x * 64 + i;
            sS2[i] = (row < NN) ? s2f[row] : 0.f;
        }
    }

    // ---- G2 ----
    const short* aBase = a2 + (size_t)(R0 + l15) * 320 + quad * 8;
    f4v acc1[4], acc2[4];
    #pragma unroll
    for (int t = 0; t < 4; ++t) { acc1[t] = (f4v){0.f,0.f,0.f,0.f}; acc2[t] = (f4v){0.f,0.f,0.f,0.f}; }
    #pragma unroll 2
    for (int s = 0; s < 10; ++s) {           // grp1: K=320 over [m|o1]
        s8v a = *(const s8v*)(aBase + s * 32);
        #pragma unroll
        for (int t = 0; t < 4; ++t) {
            s8v b = *(const s8v*)(bgA + ((size_t)(t*10 + s)*64 + lane)*8);
            acc1[t] = __builtin_amdgcn_mfma_f32_16x16x32_bf16(a, b, acc1[t], 0, 0, 0);
        }
    }
    #pragma unroll 2
    for (int s = 0; s < 8; ++s) {            // grp2: K=256 over o1
        s8v a = *(const s8v*)(aBase + 64 + s * 32);
        #pragma unroll
        for (int t = 0; t < 4; ++t) {
            s8v b = *(const s8v*)(bgB + ((size_t)(t*8 + s)*64 + lane)*8);
            acc2[t] = __builtin_amdgcn_mfma_f32_16x16x32_bf16(a, b, acc2[t], 0, 0, 0);
        }
    }
    __syncthreads();
    #pragma unroll
    for (int t = 0; t < 4; ++t)
        #pragma unroll
        for (int r = 0; r < 4; ++r) {
            int lr = w*16 + quad*4 + r;
            float v = acc1[t][r] + sS2[lr] * acc2[t][r];
            sm[lr * 72 + t*16 + l15] = f2b(v);
        }
    __syncthreads();

    // ---- G3 per sub-tile: A = [out_pre | x] (K=128) ----
    const short* arow = sm + (w*16 + l15) * 72 + quad * 8;
    s8v p0 = *(const s8v*)(arow);
    s8v p1 = *(const s8v*)(arow + 32);
    const short* xrow = xb + (size_t)(R0 + l15) * 64 + quad * 8;
    s8v q0 = *(const s8v*)(xrow);
    s8v q1 = *(const s8v*)(xrow + 32);

    #pragma unroll 1
    for (int t = 0; t < 4; ++t) {
        f4v ga[4];                            // r, z, n, h accumulators for cols t*16..+15
        #pragma unroll
        for (int g = 0; g < 4; ++g) {
            const short* bb = bg3 + ((size_t)((g*4 + t)*4)*64 + lane)*8;
            f4v a = (f4v){0.f,0.f,0.f,0.f};
            a = __builtin_amdgcn_mfma_f32_16x16x32_bf16(p0, *(const s8v*)(bb),          a, 0, 0, 0);
            a = __builtin_amdgcn_mfma_f32_16x16x32_bf16(p1, *(const s8v*)(bb +  512),   a, 0, 0, 0);
            a = __builtin_amdgcn_mfma_f32_16x16x32_bf16(q0, *(const s8v*)(bb + 1024),   a, 0, 0, 0);
            a = __builtin_amdgcn_mfma_f32_16x16x32_bf16(q1, *(const s8v*)(bb + 1536),   a, 0, 0, 0);
            ga[g] = a;
        }
        int c = t*16 + l15;
        float br = b4[c], bz = b4[64 + c], bn = b4[128 + c], bh = b4[192 + c];
        #pragma unroll
        for (int r = 0; r < 4; ++r) {
            int row = R0 + quad*4 + r;
            if (row >= NN) continue;
            float rr = 1.f / (1.f + expf(-(ga[0][r] + br)));
            float zz = 1.f / (1.f + expf(-(ga[1][r] + bz)));
            float nn = tanhf(fmaf(rr, ga[3][r] + bh, ga[2][r] + bn));
            out[(size_t)row*64 + c] = (1.f - zz)*nn + zz*x[(size_t)row*64 + c];
        }
    }
}

extern "C" void kernel_launch(void* const* d_in, const int* in_sizes, int n_in,
                              void* d_out, int out_size, void* d_ws, size_t ws_size,
                              hipStream_t stream)
{
    const float* x     = (const float*)d_in[0];
    const float* eattr = (const float*)d_in[1];
    const float* dh    = (const float*)d_in[2];
    const float* W     = (const float*)d_in[3];
    const float* We    = (const float*)d_in[4];
    const float* be    = (const float*)d_in[5];
    const float* Wpre  = (const float*)d_in[6];
    const float* bpre  = (const float*)d_in[7];
    const float* Wpost = (const float*)d_in[8];
    const float* bpost = (const float*)d_in[9];
    const float* Wih   = (const float*)d_in[10];
    const float* bih   = (const float*)d_in[11];
    const float* Whh   = (const float*)d_in[12];
    const float* bhh   = (const float*)d_in[13];
    const int*   eidx  = (const int*)d_in[14];
    unsigned char* wsb = (unsigned char*)d_ws;
    float* out = (float*)d_out;
    const int* srcA = eidx;
    const int* dstA = eidx + NE;
    int* cnt  = (int*)(wsb + B_CNT);
    int* offs = (int*)(wsb + B_OFFS);
    int* rank = (int*)(wsb + B_RANK);
    int* roff = (int*)(wsb + B_ROFF);
    int2* el2 = (int2*)(wsb + B_EL2);
    int* part = (int*)(wsb + B_PART);

    hipMemsetAsync(wsb + B_SUML, 0, 4, stream);
    hipMemsetAsync(cnt, 0, REP * NN * sizeof(int), stream);

    k_prep    <<<3125, 256, 0, stream>>>(x, dh, dstA, W, Wpre, We, be, bpost,
                                         Wpost, Wih, bih, Whh, bhh, cnt, rank, wsb);
    k_scanA   <<<SCAN_B, 256, 0, stream>>>(cnt, offs, roff, part);
    k_scanC   <<<SCAN_B, 256, 0, stream>>>(part, offs, roff);
    k_scatter <<<NE/256, 256, 0, stream>>>(srcA, dstA, rank, roff, el2);
    k_g1      <<<NNP/64, 256, 0, stream>>>(wsb);
    k_agg     <<<2048, 256, 0, stream>>>(eattr, bpre, wsb);
    k_g23     <<<NNP/64, 256, 0, stream>>>(x, wsb, out);
}

// Round 11
// 249.146 us; speedup vs baseline: 1.2443x; 1.0195x over previous
//
#include <hip/hip_runtime.h>
#include <math.h>

#define NN  50000
#define NNP 50048
#define NE  800000
#define REP 16

// ---- workspace byte offsets ----
#define B_BG1   0u          // g1 B frags: 12 tiles x 2 ks x 512 bf16 = 24576 B
#define B_BG2A  24576u      // g2 grp1 frags: 4 x 10 x 512 bf16 = 40960 B
#define B_BG2B  65536u      // g2 grp2 frags: 4 x 8 x 512 bf16 = 32768 B
#define B_BG3   98304u      // g3 stacked frags: 16 x 4 x 512 bf16 = 65536 B
#define B_WE2   163840u     // 3x64 f32
#define B_BE2   164608u     // 64 f32
#define B_B4    164864u     // 256 f32 GRU bias [b3r+bhhr | b3z+bhhz | b3n | bhhn]
#define B_SUML  165888u     // 1 f32
#define B_XB    166912u     // x bf16: NNP*64
#define B_NF    6573056u    // [md2|ms2] bf16: NNP*128 (256 B/row)
#define B_A2    19385344u   // [m | o1-interleaved] bf16: NNP*320 (640 B/row)
#define B_S2F   51416064u   // NN f32
#define B_CNT   51616064u   // REP*NN int
#define B_OFFS  54816064u   // NN+1 int
#define B_RANK  55016072u   // NE int
#define B_ROFF  58216072u   // NN*REP int
#define B_EL2   61416072u   // NE int2 (e, src)
#define B_PART  67816072u   // 196 int
// end ~67.8 MB

#define SCAN_B  196

typedef __attribute__((ext_vector_type(8))) short s8v;
typedef __attribute__((ext_vector_type(4))) short s4v;
typedef __attribute__((ext_vector_type(4))) float f4v;

__device__ inline short f2b(float f){
    union { float f; unsigned u; } v; v.f = f;
    unsigned r = v.u + 0x7fffu + ((v.u >> 16) & 1u);
    return (short)(r >> 16);
}
__device__ inline float b2f(short b){
    union { unsigned u; float f; } v; v.u = ((unsigned)(unsigned short)b) << 16;
    return v.f;
}

// ---- k_fold: U1/U2 = W @ Wpre{1,2}, LDS-staged (was the 40us tail in k_prep) ----
// 4 blocks: b 0,1 -> U1 (bg1 ts 8..15), b 2,3 -> U2 (ts 16..23). Same f32
// summation order as before -> bit-identical packed frags.
__global__ __launch_bounds__(256) void k_fold(const float* __restrict__ W,
    const float* __restrict__ Wpre, unsigned char* __restrict__ wsb)
{
    __shared__ float sWT[64 * 68];           // W transposed, row stride 68 (16B-aligned)
    __shared__ float sP[64 * 64];            // Wpre half, as-is layout
    int b = blockIdx.x, t = threadIdx.x;
    const float* wp = Wpre + ((b < 2) ? 0 : 4096);
    // stage: 4096 floats each, coalesced float4 loads
    #pragma unroll
    for (int q = 0; q < 4; ++q) {
        int li = q * 1024 + t * 4;
        int r = li >> 6, c0 = li & 63;
        float4 wv = *(const float4*)(W + r * 64 + c0);
        sWT[(c0 + 0) * 68 + r] = wv.x;
        sWT[(c0 + 1) * 68 + r] = wv.y;
        sWT[(c0 + 2) * 68 + r] = wv.z;
        sWT[(c0 + 3) * 68 + r] = wv.w;
        *(float4*)(sP + r * 64 + c0) = *(const float4*)(wp + r * 64 + c0);
    }
    __syncthreads();

    int w = t >> 6, lane = t & 63;
    int quad = lane >> 4, l15 = lane & 15;
    int ts = 8 + b * 4 + w;                  // global bg1 tile-step
    int tt = ts >> 1, s = ts & 1;
    int th = (b < 2) ? (tt - 4) : (tt - 8);  // tile within the 64-col half
    int nn = th * 16 + l15;
    int k0 = s * 32 + quad * 8;
    float acc[8];
    #pragma unroll
    for (int j = 0; j < 8; ++j) acc[j] = 0.f;
    for (int c = 0; c < 64; ++c) {
        float pv = sP[c * 64 + nn];          // broadcast across quads (free)
        const float4* w4 = (const float4*)&sWT[c * 68 + k0];
        float4 f0 = w4[0], f1 = w4[1];
        acc[0] = fmaf(f0.x, pv, acc[0]); acc[1] = fmaf(f0.y, pv, acc[1]);
        acc[2] = fmaf(f0.z, pv, acc[2]); acc[3] = fmaf(f0.w, pv, acc[3]);
        acc[4] = fmaf(f1.x, pv, acc[4]); acc[5] = fmaf(f1.y, pv, acc[5]);
        acc[6] = fmaf(f1.z, pv, acc[6]); acc[7] = fmaf(f1.w, pv, acc[7]);
    }
    short* dst = (short*)(wsb + B_BG1);
    #pragma unroll
    for (int j = 0; j < 8; ++j)
        dst[((size_t)ts * 64 + lane) * 8 + j] = f2b(acc[j]);
}

// ---- k_prep: weight pack (direct) + xcast + replicated count(+rank) + avglog ----
__global__ __launch_bounds__(256) void k_prep(const float* __restrict__ x,
    const float* __restrict__ dh, const int* __restrict__ dstA,
    const float* __restrict__ W, const float* __restrict__ Wpre,
    const float* __restrict__ We, const float* __restrict__ be,
    const float* __restrict__ bpost, const float* __restrict__ Wpost,
    const float* __restrict__ Wih, const float* __restrict__ bih,
    const float* __restrict__ Whh, const float* __restrict__ bhh,
    int* __restrict__ cnt, int* __restrict__ rank,
    unsigned char* __restrict__ wsb)
{
    __shared__ float sred[4];
    int b = blockIdx.x, t = threadIdx.x;
    {   // degree count + rank into replica (b & 15)
        int e = b * 256 + t;
        int r = b & (REP - 1);
        rank[e] = atomicAdd(&cnt[r * NN + dstA[e]], 1);
    }

    if (b < 42) {                            // job: weight pack (U-fold moved to k_fold)
        int idx = b * 256 + t;
        int lane = idx & 63;
        int quad = lane >> 4, l15 = lane & 15;
        if (idx < 512) {                     // bg1 W tiles (ts 0..7, n<64)
            short* dst = (short*)(wsb + B_BG1);
            int ts = idx >> 6;
            int tt = ts >> 1, s = ts & 1;
            int n = tt*16 + l15;
            for (int j = 0; j < 8; ++j) {
                int k = s*32 + quad*8 + j;
                dst[((size_t)ts*64 + lane)*8 + j] = f2b(W[k*64 + n]);
            }
        } else if (idx < 1536) {
            // U1/U2 tiles handled by k_fold
        } else if (idx < 4096) {             // bg2a: [Wp_m; W1+W3 interleaved-K] (320 x 64)
            int id = idx - 1536;
            short* dst = (short*)(wsb + B_BG2A);
            int ts = id >> 6;                // tt*10+s
            int tt = ts / 10, s = ts % 10;
            int n = tt*16 + l15;
            for (int j = 0; j < 8; ++j) {
                int k = s*32 + quad*8 + j;   // 0..319 (a2 K order)
                float v;
                if (k < 64) v = Wpost[k*64 + n];
                else {                       // o1 interleaved: k=64+ch*4+st
                    int kk = k - 64, ch = kk >> 2, st = kk & 3;
                    int ok = 64 + st*64 + ch;
                    v = Wpost[ok*64 + n] + Wpost[(ok + 512)*64 + n];  // o3==o1 fold
                }
                dst[((size_t)ts*64 + lane)*8 + j] = f2b(v);
            }
        } else if (idx < 6144) {             // bg2b: W2 interleaved-K (256 x 64)
            int id = idx - 4096;
            short* dst = (short*)(wsb + B_BG2B);
            int ts = id >> 6;                // tt*8+s
            int tt = ts / 8, s = ts % 8;
            int n = tt*16 + l15;
            for (int j = 0; j < 8; ++j) {
                int k = s*32 + quad*8 + j;
                int ch = k >> 2, st = k & 3;
                int ok = 320 + st*64 + ch;
                dst[((size_t)ts*64 + lane)*8 + j] = f2b(Wpost[ok*64 + n]);
            }
        } else if (idx < 10240) {            // bg3: [[Wih_r,Wih_z,Wih_n,0],[Whh_r,Whh_z,0,Whh_n]] (128 x 256)
            int id = idx - 6144;
            short* dst = (short*)(wsb + B_BG3);
            int ts = id >> 6;                // 0..63 = tile*4+s
            int tt = ts >> 2, s = ts & 3;
            int n = tt*16 + l15;             // 0..255
            for (int j = 0; j < 8; ++j) {
                int k = s*32 + quad*8 + j;   // 0..127
                float v;
                if (k < 64) v = (n < 192) ? Wih[k*192 + n] : 0.f;
                else {
                    int kk = k - 64;
                    if (n < 128)      v = Whh[kk*192 + n];
                    else if (n < 192) v = 0.f;
                    else              v = Whh[kk*192 + 128 + (n - 192)];
                }
                dst[((size_t)ts*64 + lane)*8 + j] = f2b(v);
            }
        } else if (idx < 10432) {            // We2 = We @ Wpre3 (3 x 64)
            int t2 = idx - 10240; int kk = t2 >> 6, j = t2 & 63;
            float v = 0.f;
            for (int c = 0; c < 64; ++c) v += We[kk*64 + c] * Wpre[(128+c)*64 + j];
            ((float*)(wsb + B_WE2))[t2] = v;
        } else if (idx < 10496) {            // be2 = be @ Wpre3
            int j = idx - 10432;
            float v = 0.f;
            for (int c = 0; c < 64; ++c) v += be[c] * Wpre[(128+c)*64 + j];
            ((float*)(wsb + B_BE2))[j] = v;
        } else if (idx < 10752) {            // b4 GRU bias table (256)
            int j = idx - 10496;
            float v;
            if (j < 192) {
                v = bih[j];
                for (int k = 0; k < 64; ++k) v += bpost[k] * Wih[k*192 + j];
                if (j < 128) v += bhh[j];
            } else v = bhh[128 + (j - 192)];
            ((float*)(wsb + B_B4))[j] = v;
        }
    } else if (b < 1605) {                   // job: x -> bf16
        int i = (b - 42) * 256 + t;
        if (i < 400000) {
            const float4* xp = (const float4*)(x + (size_t)i * 8);
            float4 p0 = xp[0], p1 = xp[1];
            s8v o;
            o[0]=f2b(p0.x); o[1]=f2b(p0.y); o[2]=f2b(p0.z); o[3]=f2b(p0.w);
            o[4]=f2b(p1.x); o[5]=f2b(p1.y); o[6]=f2b(p1.z); o[7]=f2b(p1.w);
            *(s8v*)((short*)(wsb + B_XB) + (size_t)i * 8) = o;
        }
    } else if (b < 1801) {                   // job: sum log(dh+1)
        int i = (b - 1605) * 256 + t;
        float v = (i < NN) ? logf(dh[i] + 1.f) : 0.f;
        #pragma unroll
        for (int m = 32; m >= 1; m >>= 1) v += __shfl_xor(v, m, 64);
        if ((t & 63) == 0) sred[t >> 6] = v;
        __syncthreads();
        if (t == 0) atomicAdd((float*)(wsb + B_SUML), sred[0]+sred[1]+sred[2]+sred[3]);
    }
}

// ---- scanA ----
__global__ __launch_bounds__(256) void k_scanA(const int* __restrict__ cnt,
    int* __restrict__ offs, int* __restrict__ roff, int* __restrict__ part)
{
    __shared__ int sh[256];
    int t = threadIdx.x, i = blockIdx.x * 256 + t;
    int v = 0;
    int pre[REP];
    if (i < NN) {
        #pragma unroll
        for (int r = 0; r < REP; ++r) { pre[r] = v; v += cnt[r * NN + i]; }
    }
    sh[t] = v; __syncthreads();
    #pragma unroll
    for (int o = 1; o < 256; o <<= 1) {
        int u = (t >= o) ? sh[t - o] : 0;
        __syncthreads();
        sh[t] += u;
        __syncthreads();
    }
    if (i < NN) {
        offs[i] = sh[t] - v;
        int4* rp = (int4*)(roff + (size_t)i * REP);
        #pragma unroll
        for (int q = 0; q < REP/4; ++q)
            rp[q] = make_int4(pre[q*4], pre[q*4+1], pre[q*4+2], pre[q*4+3]);
    }
    if (t == 255) part[blockIdx.x] = sh[255];
}

// ---- scanC ----
__global__ __launch_bounds__(256) void k_scanC(const int* __restrict__ part,
    int* __restrict__ offs, int* __restrict__ roff)
{
    __shared__ int sh[256];
    int b = blockIdx.x, t = threadIdx.x;
    int v = (t < SCAN_B) ? part[t] : 0;
    sh[t] = v; __syncthreads();
    #pragma unroll
    for (int o = 1; o < 256; o <<= 1) {
        int u = (t >= o) ? sh[t - o] : 0;
        __syncthreads();
        sh[t] += u;
        __syncthreads();
    }
    int base = (b == 0) ? 0 : sh[b - 1];
    int i = b * 256 + t;
    if (i < NN) {
        int fo = offs[i] + base;
        offs[i] = fo;
        int4* rp = (int4*)(roff + (size_t)i * REP);
        #pragma unroll
        for (int q = 0; q < REP/4; ++q) {
            int4 r4 = rp[q];
            r4.x += fo; r4.y += fo; r4.z += fo; r4.w += fo;
            rp[q] = r4;
        }
    }
    if (b == 0 && t == 0) offs[NN] = NE;
}

// ---- scatter: no atomics ----
__global__ __launch_bounds__(256) void k_scatter(const int* __restrict__ srcA,
    const int* __restrict__ dstA, const int* __restrict__ rank,
    const int* __restrict__ roff, int2* __restrict__ el2)
{
    int e = blockIdx.x * 256 + threadIdx.x;
    int r = blockIdx.x & (REP - 1);
    int dst = dstA[e];
    int p = roff[dst * REP + r] + rank[e];
    el2[p] = make_int2(e, srcA[e]);
}

// ---- G1 (MFMA): x @ [W|U1|U2] -> a2(m), nf(md2|ms2) ----
__global__ __launch_bounds__(256) void k_g1(unsigned char* __restrict__ wsb)
{
    const short* xb = (const short*)(wsb + B_XB);
    const short* bf = (const short*)(wsb + B_BG1);
    short* a2 = (short*)(wsb + B_A2);
    short* nf = (short*)(wsb + B_NF);
    int w = threadIdx.x >> 6, lane = threadIdx.x & 63;
    int quad = lane >> 4, l15 = lane & 15;
    int R0 = blockIdx.x * 64 + w * 16;
    const short* arow = xb + (size_t)(R0 + l15) * 64 + quad * 8;
    s8v a0 = *(const s8v*)(arow);
    s8v a1 = *(const s8v*)(arow + 32);
    f4v acc[12];
    #pragma unroll
    for (int t = 0; t < 12; ++t) acc[t] = (f4v){0.f,0.f,0.f,0.f};
    #pragma unroll
    for (int t = 0; t < 12; ++t) {
        s8v b0 = *(const s8v*)(bf + ((size_t)(t*2+0)*64 + lane)*8);
        s8v b1 = *(const s8v*)(bf + ((size_t)(t*2+1)*64 + lane)*8);
        acc[t] = __builtin_amdgcn_mfma_f32_16x16x32_bf16(a0, b0, acc[t], 0, 0, 0);
        acc[t] = __builtin_amdgcn_mfma_f32_16x16x32_bf16(a1, b1, acc[t], 0, 0, 0);
    }
    #pragma unroll
    for (int t = 0; t < 12; ++t) {
        #pragma unroll
        for (int r = 0; r < 4; ++r) {
            int row = R0 + quad*4 + r;
            if (row >= NN) continue;
            short v = f2b(acc[t][r]);
            if (t < 4) a2[(size_t)row*320 + t*16 + l15] = v;
            else       nf[(size_t)row*128 + (t-4)*16 + l15] = v;
        }
    }
}

// ---- aggregation: grid-stride wave-per-node ----
__global__ __launch_bounds__(256) void k_agg(const float* __restrict__ eattr,
    const float* __restrict__ bpre, unsigned char* __restrict__ wsb)
{
    __shared__ float4 sEA[4][64];
    __shared__ int    sOFF[4][64];
    int lane = threadIdx.x & 63;
    int w    = threadIdx.x >> 6;
    int wid  = blockIdx.x * 4 + w;
    const int* offs = (const int*)(wsb + B_OFFS);
    const int2* el2 = (const int2*)(wsb + B_EL2);
    const unsigned char* nfb = wsb + B_NF;
    const short* nf = (const short*)(wsb + B_NF);
    const float* we2p = (const float*)(wsb + B_WE2);
    float we0 = we2p[lane], we1 = we2p[64 + lane], we2v = we2p[128 + lane];
    float be2l = ((const float*)(wsb + B_BE2))[lane];
    float bprel = bpre[lane];
    float rcpavg = (float)NN / ((const float*)(wsb + B_SUML))[0];
    const float4* e4 = (const float4*)eattr;
    unsigned laneoff = 128u + 2u * (unsigned)lane;
    short* a2b = (short*)(wsb + B_A2);
    float* s2f = (float*)(wsb + B_S2F);

    for (int n = wid; n < NN; n += 8192) {
        float md2l = b2f(nf[(size_t)n * 128 + lane]);
        float tbase = md2l + be2l;
        int o0 = offs[n], o1e = offs[n + 1];
        float s = 0.f, ss = 0.f, mn = INFINITY, mx = -INFINITY;
        for (int base = o0; base < o1e; base += 64) {
            int cnt = o1e - base; if (cnt > 64) cnt = 64;
            if (lane < cnt) {
                int2 es = el2[base + lane];
                sOFF[w][lane] = es.y << 8;
                sEA[w][lane]  = e4[es.x];
            }
            for (int d0 = 0; d0 < cnt; d0 += 8) {
                float msv[8];
                #pragma unroll
                for (int u = 0; u < 8; ++u) {
                    int d = d0 + u; if (d > cnt - 1) d = cnt - 1;
                    unsigned off = (unsigned)sOFF[w][d] + laneoff;
                    msv[u] = b2f(*(const short*)(nfb + off));
                }
                #pragma unroll
                for (int u = 0; u < 8; ++u) {
                    int d = d0 + u;
                    if (d < cnt) {
                        float4 ea = sEA[w][d];
                        float t = tbase + msv[u];
                        t = fmaf(ea.x, we0, t);
                        t = fmaf(ea.y, we1, t);
                        t = fmaf(ea.z, we2v, t);
                        float h = fmaf(ea.w, t, bprel);
                        s += h; ss = fmaf(h, h, ss);
                        mn = fminf(mn, h); mx = fmaxf(mx, h);
                    }
                }
            }
        }
        int deg = o1e - o0;
        float safe = (float)(deg > 0 ? deg : 1);
        float mean = s / safe;
        float var  = ss / safe - mean * mean;
        float stdv = sqrtf(fmaxf(var, 0.f) + 1e-5f);
        if (deg == 0) { mn = 0.f; mx = 0.f; }
        s4v o; o[0] = f2b(mean); o[1] = f2b(mn); o[2] = f2b(mx); o[3] = f2b(stdv);
        *(s4v*)(a2b + (size_t)n * 320 + 64 + (lane << 2)) = o;
        if (lane == 0) s2f[n] = logf(safe + 1.f) * rcpavg;
    }
}

// ---- G2+G3 fused: spill-free per-sub-tile schedule ----
__global__ __launch_bounds__(256) void k_g23(const float* __restrict__ x,
    unsigned char* __restrict__ wsb, float* __restrict__ out)
{
    __shared__ short sm[64 * 72];            // out_pre tile, row stride 72
    __shared__ float sS2[64];
    const short* a2  = (const short*)(wsb + B_A2);
    const short* xb  = (const short*)(wsb + B_XB);
    const short* bgA = (const short*)(wsb + B_BG2A);
    const short* bgB = (const short*)(wsb + B_BG2B);
    const short* bg3 = (const short*)(wsb + B_BG3);
    const float* b4  = (const float*)(wsb + B_B4);
    const float* s2f = (const float*)(wsb + B_S2F);
    int w = threadIdx.x >> 6, lane = threadIdx.x & 63;
    int quad = lane >> 4, l15 = lane & 15;
    int R0 = blockIdx.x * 64 + w * 16;

    {   // s2 tile
        int i = threadIdx.x;
        if (i < 64) {
            int row = blockIdx.x * 64 + i;
            sS2[i] = (row < NN) ? s2f[row] : 0.f;
        }
    }

    // ---- G2 ----
    const short* aBase = a2 + (size_t)(R0 + l15) * 320 + quad * 8;
    f4v acc1[4], acc2[4];
    #pragma unroll
    for (int t = 0; t < 4; ++t) { acc1[t] = (f4v){0.f,0.f,0.f,0.f}; acc2[t] = (f4v){0.f,0.f,0.f,0.f}; }
    #pragma unroll 2
    for (int s = 0; s < 10; ++s) {           // grp1: K=320 over [m|o1]
        s8v a = *(const s8v*)(aBase + s * 32);
        #pragma unroll
        for (int t = 0; t < 4; ++t) {
            s8v b = *(const s8v*)(bgA + ((size_t)(t*10 + s)*64 + lane)*8);
            acc1[t] = __builtin_amdgcn_mfma_f32_16x16x32_bf16(a, b, acc1[t], 0, 0, 0);
        }
    }
    #pragma unroll 2
    for (int s = 0; s < 8; ++s) {            // grp2: K=256 over o1
        s8v a = *(const s8v*)(aBase + 64 + s * 32);
        #pragma unroll
        for (int t = 0; t < 4; ++t) {
            s8v b = *(const s8v*)(bgB + ((size_t)(t*8 + s)*64 + lane)*8);
            acc2[t] = __builtin_amdgcn_mfma_f32_16x16x32_bf16(a, b, acc2[t], 0, 0, 0);
        }
    }
    __syncthreads();
    #pragma unroll
    for (int t = 0; t < 4; ++t)
        #pragma unroll
        for (int r = 0; r < 4; ++r) {
            int lr = w*16 + quad*4 + r;
            float v = acc1[t][r] + sS2[lr] * acc2[t][r];
            sm[lr * 72 + t*16 + l15] = f2b(v);
        }
    __syncthreads();

    // ---- G3 per sub-tile: A = [out_pre | x] (K=128) ----
    const short* arow = sm + (w*16 + l15) * 72 + quad * 8;
    s8v p0 = *(const s8v*)(arow);
    s8v p1 = *(const s8v*)(arow + 32);
    const short* xrow = xb + (size_t)(R0 + l15) * 64 + quad * 8;
    s8v q0 = *(const s8v*)(xrow);
    s8v q1 = *(const s8v*)(xrow + 32);

    #pragma unroll 1
    for (int t = 0; t < 4; ++t) {
        f4v ga[4];                            // r, z, n, h accumulators for cols t*16..+15
        #pragma unroll
        for (int g = 0; g < 4; ++g) {
            const short* bb = bg3 + ((size_t)((g*4 + t)*4)*64 + lane)*8;
            f4v a = (f4v){0.f,0.f,0.f,0.f};
            a = __builtin_amdgcn_mfma_f32_16x16x32_bf16(p0, *(const s8v*)(bb),          a, 0, 0, 0);
            a = __builtin_amdgcn_mfma_f32_16x16x32_bf16(p1, *(const s8v*)(bb +  512),   a, 0, 0, 0);
            a = __builtin_amdgcn_mfma_f32_16x16x32_bf16(q0, *(const s8v*)(bb + 1024),   a, 0, 0, 0);
            a = __builtin_amdgcn_mfma_f32_16x16x32_bf16(q1, *(const s8v*)(bb + 1536),   a, 0, 0, 0);
            ga[g] = a;
        }
        int c = t*16 + l15;
        float br = b4[c], bz = b4[64 + c], bn = b4[128 + c], bh = b4[192 + c];
        #pragma unroll
        for (int r = 0; r < 4; ++r) {
            int row = R0 + quad*4 + r;
            if (row >= NN) continue;
            float rr = 1.f / (1.f + expf(-(ga[0][r] + br)));
            float zz = 1.f / (1.f + expf(-(ga[1][r] + bz)));
            float nn = tanhf(fmaf(rr, ga[3][r] + bh, ga[2][r] + bn));
            out[(size_t)row*64 + c] = (1.f - zz)*nn + zz*x[(size_t)row*64 + c];
        }
    }
}

extern "C" void kernel_launch(void* const* d_in, const int* in_sizes, int n_in,
                              void* d_out, int out_size, void* d_ws, size_t ws_size,
                              hipStream_t stream)
{
    const float* x     = (const float*)d_in[0];
    const float* eattr = (const float*)d_in[1];
    const float* dh    = (const float*)d_in[2];
    const float* W     = (const float*)d_in[3];
    const float* We    = (const float*)d_in[4];
    const float* be    = (const float*)d_in[5];
    const float* Wpre  = (const float*)d_in[6];
    const float* bpre  = (const float*)d_in[7];
    const float* Wpost = (const float*)d_in[8];
    const float* bpost = (const float*)d_in[9];
    const float* Wih   = (const float*)d_in[10];
    const float* bih   = (const float*)d_in[11];
    const float* Whh   = (const float*)d_in[12];
    const float* bhh   = (const float*)d_in[13];
    const int*   eidx  = (const int*)d_in[14];
    unsigned char* wsb = (unsigned char*)d_ws;
    float* out = (float*)d_out;
    const int* srcA = eidx;
    const int* dstA = eidx + NE;
    int* cnt  = (int*)(wsb + B_CNT);
    int* offs = (int*)(wsb + B_OFFS);
    int* rank = (int*)(wsb + B_RANK);
    int* roff = (int*)(wsb + B_ROFF);
    int2* el2 = (int2*)(wsb + B_EL2);
    int* part = (int*)(wsb + B_PART);

    hipMemsetAsync(wsb + B_SUML, 0, 4, stream);
    hipMemsetAsync(cnt, 0, REP * NN * sizeof(int), stream);

    k_fold    <<<4, 256, 0, stream>>>(W, Wpre, wsb);
    k_prep    <<<3125, 256, 0, stream>>>(x, dh, dstA, W, Wpre, We, be, bpost,
                                         Wpost, Wih, bih, Whh, bhh, cnt, rank, wsb);
    k_scanA   <<<SCAN_B, 256, 0, stream>>>(cnt, offs, roff, part);
    k_scanC   <<<SCAN_B, 256, 0, stream>>>(part, offs, roff);
    k_scatter <<<NE/256, 256, 0, stream>>>(srcA, dstA, rank, roff, el2);
    k_g1      <<<NNP/64, 256, 0, stream>>>(wsb);
    k_agg     <<<2048, 256, 0, stream>>>(eattr, bpre, wsb);
    k_g23     <<<NNP/64, 256, 0, stream>>>(x, wsb, out);
}